// Round 5
// baseline (1372.605 us; speedup 1.0000x reference)
//
#include <hip/hip_runtime.h>
#include <math.h>

#define CAPT 20480              // per-type compacted-node capacity (actual ~16.7k)
#define R2   (2*CAPT)

typedef __attribute__((ext_vector_type(8))) short short8;
typedef __attribute__((ext_vector_type(4))) float f32x4;

// ---- fast transcendentals: v_exp_f32 / v_rcp_f32 based; err ~1e-7 << bf16 ulp ----
__device__ __forceinline__ float fexp2_(float x){ return __builtin_amdgcn_exp2f(x); }
__device__ __forceinline__ float frcp_(float x){ return __builtin_amdgcn_rcpf(x); }
__device__ __forceinline__ float ftanh_(float x){
  float ax = __builtin_fabsf(x);
  float t = fexp2_(-2.885390082f * ax);          // e^{-2|x|}
  float r = (1.f - t) * frcp_(1.f + t);
  return __builtin_copysignf(r, x);
}
__device__ __forceinline__ float fsig_(float x){
  return frcp_(1.f + fexp2_(-1.442695041f * x));
}
__device__ __forceinline__ float fgelu_(float x){
  const float c = 0.7978845608028654f;
  return 0.5f*x*(1.f + ftanh_(c*(x + 0.044715f*x*x*x)));
}
__device__ __forceinline__ unsigned short f2bf(float x){
  unsigned int u = __float_as_uint(x);
  return (unsigned short)((u + 0x7FFFu + ((u>>16)&1u)) >> 16);
}
__device__ __forceinline__ float bf2f(unsigned short v){
  return __uint_as_float(((unsigned int)v) << 16);
}

// ---------------- weight prep: transposed bf16 B arena, padded to 16-mult segments ----
// Arena layout (bf16 elems):
//  [0..6)      plain msg li:  [160][96]   off = li*15360
//  [6..12)     plain upd li:  [80][160]   off = 92160 + li*12800
//  [12..14)    ar msg blk:    [320][160]  off = 168960 + blk*51200
//  [14..16)    ar upd blk:    [80][320]   off = 271360 + blk*25600
//  [16..18)    gru typ:       [256][128]  off = 322560 + typ*32768
__global__ void k_prepB(const float* __restrict__ Wm_plain, const float* __restrict__ Wu_plain,
                        const float* __restrict__ Wm_ar, const float* __restrict__ Wu_ar,
                        const float* __restrict__ Wi_map, const float* __restrict__ Wh_map,
                        const float* __restrict__ Wi_mem, const float* __restrict__ Wh_mem,
                        unsigned short* __restrict__ BtArena){
  int id = blockIdx.y;
  int Kp, elems, off;
  if (id < 6){ Kp=96;  elems=15360; off=id*15360; }
  else if (id < 12){ Kp=160; elems=12800; off=92160+(id-6)*12800; }
  else if (id < 14){ Kp=160; elems=51200; off=168960+(id-12)*51200; }
  else if (id < 16){ Kp=320; elems=25600; off=271360+(id-14)*25600; }
  else { Kp=128; elems=32768; off=322560+(id-16)*32768; }
  for (int g = blockIdx.x*256 + threadIdx.x; g < elems; g += 8*256){
    int c = g / Kp, k = g - c*Kp;
    float val = 0.f;
    if (id < 6){
      int li = id; int t = (c >= 80); int cc = c - t*80;
      if (cc < 70 && k < 70) val = Wm_plain[((li*2+t)*70 + k)*70 + cc];
    } else if (id < 12){
      int li = id-6;
      int kk = (k < 70) ? k : ((k >= 80 && k < 150) ? 70 + (k-80) : -1);
      if (c < 70 && kk >= 0) val = Wu_plain[(li*140 + kk)*70 + c];
    } else if (id < 14){
      int blk = id-12; int t = (c >= 160); int cc = c - t*160;
      int kk = (k < 70) ? k : ((k >= 80 && k < 150) ? 70 + (k-80) : -1);
      if (cc < 140 && kk >= 0) val = Wm_ar[(((blk*2+t)*140) + kk)*140 + cc];
    } else if (id < 16){
      int blk = id-14;
      int kk = (k < 70) ? k : ((k >= 80 && k < 150) ? 70 + (k-80)
               : ((k >= 160 && k < 300) ? 140 + (k-160) : -1));
      if (c < 70 && kk >= 0) val = Wu_ar[(blk*280 + kk)*70 + c];
    } else {
      int typ = id-16;
      const float* Wi = typ ? Wi_mem : Wi_map;
      const float* Wh = typ ? Wh_mem : Wh_map;
      if (c < 192) val = (k < 64) ? Wi[c*64 + k] : Wh[c*64 + (k-64)];
      else { int cc = c-192; val = (k >= 64) ? Wh[(128+cc)*64 + (k-64)] : 0.f; }
    }
    BtArena[off + g] = f2bf(val);
  }
}

// bias arena (fp32): [0..960) plain msg [160]x6; [960..1440) plain upd [80]x6;
// [1440..2080) ar msg [320]x2; [2080..2240) ar upd [80]x2; [2240..2752) gru [256]x2
__global__ void k_prepBias(const float* __restrict__ bm_plain, const float* __restrict__ bu_plain,
                           const float* __restrict__ bm_ar, const float* __restrict__ bu_ar,
                           const float* __restrict__ bi_map, const float* __restrict__ bh_map,
                           const float* __restrict__ bi_mem, const float* __restrict__ bh_mem,
                           float* __restrict__ biasA){
  for (int g = threadIdx.x; g < 2752; g += 256){
    float val = 0.f;
    if (g < 960){ int li=g/160, c=g%160; int t=(c>=80); int cc=c-t*80;
      if (cc<70) val = bm_plain[(li*2+t)*70 + cc]; }
    else if (g < 1440){ int u=g-960; int li=u/80, c=u%80; if (c<70) val = bu_plain[li*70+c]; }
    else if (g < 2080){ int u=g-1440; int blk=u/320, c=u%320; int t=(c>=160); int cc=c-t*160;
      if (cc<140) val = bm_ar[(blk*2+t)*140 + cc]; }
    else if (g < 2240){ int u=g-2080; int blk=u/80, c=u%80; if (c<70) val = bu_ar[blk*70+c]; }
    else { int u=g-2240; int typ=u/256, c=u%256;
      const float* bi = typ ? bi_mem : bi_map; const float* bh = typ ? bh_mem : bh_map;
      val = (c < 192) ? (bi[c]+bh[c]) : bh[128 + (c-192)]; }
    biasA[g] = val;
  }
}

// ---------------- embed -> bf16 table (1.28 MB, L2-resident for the gather) ----------
__global__ void k_prepEmb(const float* __restrict__ embed, unsigned short* __restrict__ embB,
                          int total){
  int g = blockIdx.x*256 + threadIdx.x;
  if (g < total) embB[g] = f2bf(embed[g]);
}

// ---------------- init h = [one_hot(type,6) | zeros] bf16, stride 80 ----------------
__global__ void k_init_h(const int* __restrict__ type_idx, unsigned short* __restrict__ h, int N){
  int g = blockIdx.x*256 + threadIdx.x;
  if (g >= N*80) return;
  int n = g / 80, c = g - n*80;
  h[g] = (c < 6 && type_idx[n] == c) ? (unsigned short)0x3F80 : (unsigned short)0;
}

__global__ void k_compact(const int* __restrict__ type_idx, int* __restrict__ idxcat,
                          int* __restrict__ cnt, int N){
  int n = blockIdx.x*256 + threadIdx.x;
  if (n >= N) return;
  int t = type_idx[n];
  if (t == 0){ int p = atomicAdd(&cnt[0],1); if (p < CAPT) idxcat[p] = n; }
  else if (t == 5){ int p = atomicAdd(&cnt[1],1); if (p < CAPT) idxcat[CAPT+p] = n; }
}

// ---------------- embed gather: Xemb[r][s][k] bf16, uint4 per thread ----------------
__global__ void k_xemb(const int* __restrict__ idxcat, const int* __restrict__ tokens,
                       const unsigned short* __restrict__ embB, unsigned short* __restrict__ Xemb){
  int g = blockIdx.x*256 + threadIdx.x;          // R2*64 threads
  if (g >= R2*64) return;
  int r = g >> 6, rem = g & 63, s = rem >> 3, ch = rem & 7;
  int nd = idxcat[r]; if (nd < 0) nd = 0;
  int tok = tokens[nd*8 + s];
  *(uint4*)&Xemb[(size_t)g*8] = *(const uint4*)&embB[tok*64 + ch*8];
}

// ---------------- CSR build ----------------
__global__ void k_count(const int* __restrict__ edst, int* __restrict__ deg, int TE){
  int i = blockIdx.x*256 + threadIdx.x;
  if (i < TE) atomicAdd(&deg[edst[i]], 1);
}
__global__ void k_scan1(const int* __restrict__ deg, int* __restrict__ off,
                        int* __restrict__ bsum, int N){
  __shared__ int sh[256];
  int t = threadIdx.x; int base = blockIdx.x*2048;
  int v[8]; int s = 0;
  for (int i=0;i<8;i++){ int g = base + t*8 + i; int x = (g<N)? deg[g] : 0; v[i]=x; s+=x; }
  sh[t]=s; __syncthreads();
  for (int o=1;o<256;o<<=1){ int x = (t>=o)? sh[t-o]:0; __syncthreads(); sh[t]+=x; __syncthreads(); }
  if (t==255) bsum[blockIdx.x] = sh[255];
  int run = sh[t]-s;
  for (int i=0;i<8;i++){ int g = base + t*8 + i; if (g<N) off[g]=run; run+=v[i]; }
}
__global__ void k_scan2(int* bsum, int nb){
  if (threadIdx.x==0 && blockIdx.x==0){ int run=0; for(int b=0;b<nb;b++){ int x=bsum[b]; bsum[b]=run; run+=x; } }
}
__global__ void k_scan3(int* __restrict__ off, const int* __restrict__ bsum, int N, int total){
  int g = blockIdx.x*256+threadIdx.x;
  if (g < N) off[g] += bsum[g>>11];
  if (g == 0) off[N] = total;
}
__global__ void k_fill(const int* __restrict__ esrc, const int* __restrict__ edst,
                       const int* __restrict__ off, int* __restrict__ cur,
                       int* __restrict__ edata, int TE, int E){
  int i = blockIdx.x*256 + threadIdx.x;
  if (i >= TE) return;
  int d = edst[i];
  int pos = off[d] + atomicAdd(&cur[d], 1);
  edata[pos] = (esrc[i] << 1) | (i >= E ? 1 : 0);
}

// ======== wgemm: B-in-registers MFMA GEMM, optional fused CSR gather-max segment ====
// C = act([A0|A1|A2] @ B + bias). Segment cols in [gLo, w012) are NOT read from
// memory directly: they are gather-maxed from gP via CSR (goff/gedata) during
// A-staging (bf16 max is exact -> bit-identical to a separate aggregate pass).
// act: 0 none, 1 gelu, 2 tanh, 3 = fused GRU cell update (CT==4, mode 1).
template<int RTR, int KT, int CT>
__global__ __launch_bounds__(256) void wgemm(
    const unsigned short* __restrict__ A0, int w0, int ldA0,
    const unsigned short* __restrict__ A1, int w1, int ldA1,
    const unsigned short* __restrict__ A2, int w2, int ldA2,
    const unsigned short* __restrict__ Bt, const unsigned short* __restrict__ Bt2, int KpB,
    const float* __restrict__ bias, const float* __restrict__ bias2,
    unsigned short* __restrict__ C, int ldC,
    int rows, int tiles, int act, int mode, const int* __restrict__ cnt,
    const int* __restrict__ goff, const int* __restrict__ gedata,
    const unsigned short* __restrict__ gP, int gldP, int goff1, int gLo)
{
  constexpr int Kpad = KT*32;
  constexpr int NRT  = RTR/16;
  constexpr int CPT  = (RTR*Kpad/8)/256;   // 16B chunks per thread per tile
  __shared__ __align__(16) unsigned short As[2][RTR*Kpad];
  int t = threadIdx.x;
  int lane = t & 63, m = lane & 15, q = lane >> 4, w = t >> 6;
  int rowBase = 0, tileBase = 0, rtEnd;
  const unsigned short* Bsel = Bt; const float* bsel = bias;
  if (mode == 1){
    rowBase = blockIdx.y * CAPT;
    int c = cnt[blockIdx.y]; if (c > CAPT) c = CAPT;
    rtEnd = (c + RTR - 1)/RTR;
    if (blockIdx.y == 1){ Bsel = Bt2; bsel = bias2; }
  } else {
    tileBase = blockIdx.y * (4*CT);
    rtEnd = (rows + RTR - 1)/RTR;
  }
  int tr = blockIdx.x;
  if (tr >= rtEnd) return;

  // ---- B fragments + bias into registers, once per block ----
  short8 breg[CT][KT]; float bv[CT]; bool val[CT]; int colr[CT];
  #pragma unroll
  for (int j=0;j<CT;j++){
    int tt = tileBase + w + 4*j;
    val[j] = (tt < tiles);
    int col = tt*16 + m;
    colr[j] = col;
    bv[j] = 0.f;
    if (val[j]){
      bv[j] = bsel[col];
      #pragma unroll
      for (int kt=0;kt<KT;kt++)
        breg[j][kt] = *(const short8*)&Bsel[(size_t)col*KpB + kt*32 + q*8];
    } else {
      #pragma unroll
      for (int kt=0;kt<KT;kt++) breg[j][kt] = (short8){0,0,0,0,0,0,0,0};
    }
  }

  int w01 = w0 + w1, w012 = w0 + w1 + w2;
  uint4 r[CPT];
  const float NEGI = -__builtin_inff();
  auto loadRegs = [&](int trr){
    #pragma unroll
    for (int i=0;i<CPT;i++){
      int c = i*256 + t;
      int row = c / (KT*4), kc = (c - row*(KT*4))*8;
      int gr = rowBase + trr*RTR + row;
      uint4 v = {0,0,0,0};
      if (gr < rows){
        if (goff && kc >= gLo){
          // fused CSR gather-max of 8 bf16 cols [kc-gLo, kc-gLo+8) for node gr
          int e0 = goff[gr], e1 = goff[gr+1];
          if (e1 > e0){
            int rel = kc - gLo;
            float f0=NEGI,f1=NEGI,f2=NEGI,f3=NEGI,f4=NEGI,f5=NEGI,f6=NEGI,f7=NEGI;
#define ACC8(vv)                                                             \
            f0=fmaxf(f0,__uint_as_float((vv).x<<16));                        \
            f1=fmaxf(f1,__uint_as_float((vv).x&0xFFFF0000u));                \
            f2=fmaxf(f2,__uint_as_float((vv).y<<16));                        \
            f3=fmaxf(f3,__uint_as_float((vv).y&0xFFFF0000u));                \
            f4=fmaxf(f4,__uint_as_float((vv).z<<16));                        \
            f5=fmaxf(f5,__uint_as_float((vv).z&0xFFFF0000u));                \
            f6=fmaxf(f6,__uint_as_float((vv).w<<16));                        \
            f7=fmaxf(f7,__uint_as_float((vv).w&0xFFFF0000u));
            int e = e0;
            for (; e + 2 <= e1; e += 2){
              int wa = gedata[e], wb = gedata[e+1];
              uint4 va = *(const uint4*)(gP + (size_t)(wa>>1)*gldP + (wa&1)*goff1 + rel);
              uint4 vb = *(const uint4*)(gP + (size_t)(wb>>1)*gldP + (wb&1)*goff1 + rel);
              ACC8(va); ACC8(vb);
            }
            if (e < e1){
              int wa = gedata[e];
              uint4 va = *(const uint4*)(gP + (size_t)(wa>>1)*gldP + (wa&1)*goff1 + rel);
              ACC8(va);
            }
#undef ACC8
            // bf16 max is a selection -> exact; repack without rounding
            v.x = (__float_as_uint(f0)>>16) | (__float_as_uint(f1)&0xFFFF0000u);
            v.y = (__float_as_uint(f2)>>16) | (__float_as_uint(f3)&0xFFFF0000u);
            v.z = (__float_as_uint(f4)>>16) | (__float_as_uint(f5)&0xFFFF0000u);
            v.w = (__float_as_uint(f6)>>16) | (__float_as_uint(f7)&0xFFFF0000u);
          }
          // else: no incoming edges -> zeros
        } else if (kc < w012){
          const unsigned short* sp;
          if (kc < w0)       sp = A0 + (size_t)gr*ldA0 + kc;
          else if (kc < w01) sp = A1 + (size_t)gr*ldA1 + (kc - w0);
          else               sp = A2 + (size_t)gr*ldA2 + (kc - w01);
          v = *(const uint4*)sp;
        }
      }
      r[i] = v;
    }
  };
  auto dsw = [&](int p){
    #pragma unroll
    for (int i=0;i<CPT;i++){
      int c = i*256 + t;
      int row = c / (KT*4), kc = (c - row*(KT*4))*8;
      *(uint4*)&As[p][row*Kpad + kc] = r[i];
    }
  };

  loadRegs(tr);
  dsw(0);
  int p = 0;
  for (;;){
    int nxt = tr + gridDim.x;
    bool hasNext = (nxt < rtEnd);
    if (hasNext) loadRegs(nxt);      // global loads (and gather) in flight across barrier
    __syncthreads();                 // buf[p] ready; prior reads of buf[p^1] done
    f32x4 acc[NRT][CT] = {};
    #pragma unroll
    for (int kt=0;kt<KT;kt++){
      short8 af[NRT];
      #pragma unroll
      for (int rt=0;rt<NRT;rt++)
        af[rt] = *(const short8*)&As[p][(rt*16+m)*Kpad + kt*32 + q*8];
      #pragma unroll
      for (int j=0;j<CT;j++)
        #pragma unroll
        for (int rt=0;rt<NRT;rt++)
          acc[rt][j] = __builtin_amdgcn_mfma_f32_16x16x32_bf16(af[rt], breg[j][kt], acc[rt][j], 0,0,0);
    }
    if constexpr (CT == 4){
      if (act == 3){
        // fused GRU cell update; Hprev == A1, u = colr[0], ldC == 64
        int u = colr[0];
        #pragma unroll
        for (int rt=0;rt<NRT;rt++){
          int rbase = rowBase + tr*RTR + rt*16 + q*4;
          #pragma unroll
          for (int i=0;i<4;i++){
            int grow = rbase + i;
            float rr = fsig_(acc[rt][0][i] + bv[0]);
            float zz = fsig_(acc[rt][1][i] + bv[1]);
            float hn = acc[rt][3][i] + bv[3];
            float nn = ftanh_(acc[rt][2][i] + bv[2] + (rr - 1.f)*hn);
            float hp = bf2f(A1[(size_t)grow*64 + u]);
            C[(size_t)grow*64 + u] = f2bf((1.f - zz)*nn + zz*hp);
          }
        }
        if (!hasNext) break;
        dsw(p^1);
        p ^= 1; tr = nxt;
        continue;
      }
    }
    bool tfull = (tr*RTR + RTR <= rows);
#define EPILOG(CHK)                                                         \
    _Pragma("unroll")                                                       \
    for (int rt=0;rt<NRT;rt++){                                             \
      int rbase = rowBase + tr*RTR + rt*16 + q*4;                           \
      _Pragma("unroll")                                                     \
      for (int j=0;j<CT;j++){                                               \
        if (!val[j]) continue;                                              \
        _Pragma("unroll")                                                   \
        for (int i=0;i<4;i++){                                              \
          int grow = rbase + i;                                             \
          if (CHK && grow >= rows) continue;                                \
          float v = acc[rt][j][i] + bv[j];                                  \
          if (act == 1) v = fgelu_(v);                                      \
          else if (act == 2) v = ftanh_(v);                                 \
          C[(size_t)grow*ldC + colr[j]] = f2bf(v);                          \
        }                                                                   \
      }                                                                     \
    }
    if (tfull){ EPILOG(false) } else { EPILOG(true) }
#undef EPILOG
    if (!hasNext) break;
    dsw(p^1);                        // safe: all reads of buf[p^1] were pre-barrier
    p ^= 1; tr = nxt;
  }
}

__global__ void k_scatter_h(const int* __restrict__ idxcat, const unsigned short* __restrict__ Hlast,
                            unsigned short* __restrict__ h){
  int g = blockIdx.x*256 + threadIdx.x;     // R2*64
  int row = g >> 6, u = g & 63;
  int nd = idxcat[row];
  if (nd >= 0) h[(size_t)nd*80 + 6 + u] = Hlast[g];
}

// ---------------- final head ----------------
__global__ void k_head(const unsigned short* __restrict__ h, const int* __restrict__ entry,
                       const float* __restrict__ W1, const float* __restrict__ b1,
                       const float* __restrict__ W2, const float* __restrict__ b2,
                       float* __restrict__ out){
  __shared__ float x[70], x1[70];
  int t = threadIdx.x;
  if (t < 70) x[t] = bf2f(h[(size_t)(*entry)*80 + t]);
  __syncthreads();
  if (t < 70){
    float s = b1[t];
    for (int i=0;i<70;i++) s += x[i]*W1[i*70 + t];
    x1[t] = fmaxf(s, 0.f);
  }
  __syncthreads();
  if (t < 640){
    float s = b2[t];
    for (int i=0;i<70;i++) s += x1[i]*W2[i*640 + t];
    out[t] = s;
  }
}

extern "C" void kernel_launch(void* const* d_in, const int* in_sizes, int n_in,
                              void* d_out, int out_size, void* d_ws, size_t ws_size,
                              hipStream_t stream) {
  const int*   tokens   = (const int*)d_in[0];
  const int*   type_idx = (const int*)d_in[1];
  const int*   esrc     = (const int*)d_in[2];
  const int*   edst     = (const int*)d_in[3];
  const int*   entry    = (const int*)d_in[4];
  const float* embed    = (const float*)d_in[5];
  const float* Wi_map   = (const float*)d_in[6];
  const float* Wh_map   = (const float*)d_in[7];
  const float* bi_map   = (const float*)d_in[8];
  const float* bh_map   = (const float*)d_in[9];
  const float* Wi_mem   = (const float*)d_in[10];
  const float* Wh_mem   = (const float*)d_in[11];
  const float* bi_mem   = (const float*)d_in[12];
  const float* bh_mem   = (const float*)d_in[13];
  const float* Wm_plain = (const float*)d_in[14];
  const float* bm_plain = (const float*)d_in[15];
  const float* Wu_plain = (const float*)d_in[16];
  const float* bu_plain = (const float*)d_in[17];
  const float* Wm_ar    = (const float*)d_in[18];
  const float* bm_ar    = (const float*)d_in[19];
  const float* Wu_ar    = (const float*)d_in[20];
  const float* bu_ar    = (const float*)d_in[21];
  const float* W1 = (const float*)d_in[22];
  const float* b1 = (const float*)d_in[23];
  const float* W2 = (const float*)d_in[24];
  const float* b2 = (const float*)d_in[25];
  float* out = (float*)d_out;

  const int N  = in_sizes[1];      // 100000
  const int TE = in_sizes[2];      // 500000
  const int E  = TE / 2;
  const int V64 = in_sizes[5];     // V*DE = 640000

  char* p = (char*)d_ws;
  auto alloc = [&](size_t bytes)->char* { char* r = p; p += (bytes + 255) & ~(size_t)255; return r; };
  unsigned short* hA  = (unsigned short*)alloc((size_t)N*80*2);
  unsigned short* hB  = (unsigned short*)alloc((size_t)N*80*2);
  unsigned short* hC  = (unsigned short*)alloc((size_t)N*80*2);
  unsigned short* P2  = (unsigned short*)alloc((size_t)N*320*2);   // also Xemb overlay
  unsigned short* Hb0 = (unsigned short*)alloc((size_t)R2*64*2);
  unsigned short* Hb1 = (unsigned short*)alloc((size_t)R2*64*2);
  int* deg    = (int*)alloc((size_t)N*4);
  int* curp   = (int*)alloc((size_t)N*4);
  int* off    = (int*)alloc((size_t)(N+8)*4);
  int* edata  = (int*)alloc((size_t)TE*4);
  int* sbsum  = (int*)alloc(256*4);
  int* cnt    = (int*)alloc(16*4);
  int* idxcat = (int*)alloc((size_t)R2*4);
  unsigned short* BtA  = (unsigned short*)alloc(388096*2);
  float* biasA = (float*)alloc(2752*4);
  unsigned short* embB = (unsigned short*)alloc((size_t)V64*2);
  unsigned short* Xemb = P2;                   // [R2][512] bf16, dead before P2 is used

  hipMemsetAsync(idxcat, 0xFF, (size_t)R2*4, stream);
  hipMemsetAsync(cnt,    0,    16*4, stream);
  hipMemsetAsync(deg,    0,    (size_t)N*4, stream);
  hipMemsetAsync(curp,   0,    (size_t)N*4, stream);
  hipMemsetAsync(Hb0,    0,    (size_t)R2*64*2, stream);

  k_prepB<<<dim3(8,18), 256, 0, stream>>>(Wm_plain, Wu_plain, Wm_ar, Wu_ar,
                                          Wi_map, Wh_map, Wi_mem, Wh_mem, BtA);
  k_prepBias<<<1, 256, 0, stream>>>(bm_plain, bu_plain, bm_ar, bu_ar,
                                    bi_map, bh_map, bi_mem, bh_mem, biasA);
  k_prepEmb<<<(V64+255)/256, 256, 0, stream>>>(embed, embB, V64);
  k_init_h<<<(N*80+255)/256, 256, 0, stream>>>(type_idx, hA, N);
  k_compact<<<(N+255)/256, 256, 0, stream>>>(type_idx, idxcat, cnt, N);

  k_count<<<(TE+255)/256, 256, 0, stream>>>(edst, deg, TE);
  int nb = (N + 2047)/2048;
  k_scan1<<<nb, 256, 0, stream>>>(deg, off, sbsum, N);
  k_scan2<<<1, 64, 0, stream>>>(sbsum, nb);
  k_scan3<<<(N+255)/256, 256, 0, stream>>>(off, sbsum, N, TE);
  k_fill<<<(TE+255)/256, 256, 0, stream>>>(esrc, edst, off, curp, edata, TE, E);

  k_xemb<<<(R2*64+255)/256, 256, 0, stream>>>(idxcat, tokens, embB, Xemb);

  // ---- GRU: 8 steps, pointwise fused into gemm epilogue (act=3) ----
  const unsigned short* BtG0 = BtA + 322560;
  const unsigned short* BtG1 = BtA + 322560 + 32768;
  const float* bG0 = biasA + 2240;
  const float* bG1 = biasA + 2240 + 256;
  unsigned short* Hcur = Hb0; unsigned short* Hnxt = Hb1;
  for (int s = 0; s < 8; s++){
    wgemm<64,4,4><<<dim3(CAPT/64, 2), 256, 0, stream>>>(
        Xemb + s*64, 64, 512,  Hcur, 64, 64,  nullptr, 0, 0,
        BtG0, BtG1, 128, bG0, bG1,
        Hnxt, 64, R2, 16, 3 /*gru fuse*/, 1, cnt,
        nullptr, nullptr, nullptr, 0, 0, 0);
    unsigned short* tmp = Hcur; Hcur = Hnxt; Hnxt = tmp;
  }
  k_scatter_h<<<(R2*64)/256, 256, 0, stream>>>(idxcat, Hcur, hA);

  // ---- 2 blocks x (3 plain MP + concat-residual AR MP); aggregate fused in upd ----
  unsigned short* cur = hA; unsigned short* f1 = hB; unsigned short* f2 = hC;
  int li = 0;
  for (int blk = 0; blk < 2; blk++){
    unsigned short* saved = cur;
    unsigned short* ins[3]  = {cur, f1, f2};
    unsigned short* outs[3] = {f1, f2, f1};
    for (int j = 0; j < 3; j++){
      unsigned short* X = ins[j]; unsigned short* Yo = outs[j];
      // msg: [N,80] @ [96->160] (both edge types fused in cols)
      wgemm<64,3,3><<<dim3(1024,1), 256, 0, stream>>>(
          X, 80, 80,  nullptr, 0, 0,  nullptr, 0, 0,
          BtA + li*15360, nullptr, 96, biasA + li*160, nullptr,
          P2, 160, N, 10, 0, 0, nullptr,
          nullptr, nullptr, nullptr, 0, 0, 0);
      // upd: [N, 80 | agg(80, gathered from P2)] @ [160->80]
      wgemm<64,5,2><<<dim3(1024,1), 256, 0, stream>>>(
          X, 80, 80,  nullptr, 80, 0,  nullptr, 0, 0,
          BtA + 92160 + li*12800, nullptr, 160, biasA + 960 + li*80, nullptr,
          Yo, 80, N, 5, 0, 0, nullptr,
          off, edata, P2, 160, 80, 80 /*gLo*/);
      li++;
    }
    // AR msg: [N,80|80] @ [160->320], gelu; y splits 20 col tiles into 12+8
    wgemm<64,5,3><<<dim3(512,2), 256, 0, stream>>>(
        saved, 80, 80,  f1, 80, 80,  nullptr, 0, 0,
        BtA + 168960 + blk*51200, nullptr, 160, biasA + 1440 + blk*320, nullptr,
        P2, 320, N, 20, 1 /*gelu*/, 0, nullptr,
        nullptr, nullptr, nullptr, 0, 0, 0);
    // AR upd: [N, 80|80 | agg(160, gathered from P2)] @ [320->80], tanh
    wgemm<32,10,2><<<dim3(1024,1), 256, 0, stream>>>(
        saved, 80, 80,  f1, 80, 80,  nullptr, 160, 0,
        BtA + 271360 + blk*25600, nullptr, 320, biasA + 2080 + blk*80, nullptr,
        f2, 80, N, 5, 2 /*tanh*/, 0, nullptr,
        off, edata, P2, 320, 160, 160 /*gLo*/);
    unsigned short* t3 = cur; cur = f2; f2 = t3;
  }

  k_head<<<1, 640, 0, stream>>>(cur, entry, W1, b1, W2, b2, out);
}

// Round 6
// 1072.424 us; speedup vs baseline: 1.2799x; 1.2799x over previous
//
#include <hip/hip_runtime.h>
#include <math.h>

#define CAPT 20480              // per-type compacted-node capacity (actual ~16.7k)
#define R2   (2*CAPT)

typedef __attribute__((ext_vector_type(8))) short short8;
typedef __attribute__((ext_vector_type(4))) float f32x4;

// ---- fast transcendentals: v_exp_f32 / v_rcp_f32 based; err ~1e-7 << bf16 ulp ----
__device__ __forceinline__ float fexp2_(float x){ return __builtin_amdgcn_exp2f(x); }
__device__ __forceinline__ float frcp_(float x){ return __builtin_amdgcn_rcpf(x); }
__device__ __forceinline__ float ftanh_(float x){
  float ax = __builtin_fabsf(x);
  float t = fexp2_(-2.885390082f * ax);          // e^{-2|x|}
  float r = (1.f - t) * frcp_(1.f + t);
  return __builtin_copysignf(r, x);
}
__device__ __forceinline__ float fsig_(float x){
  return frcp_(1.f + fexp2_(-1.442695041f * x));
}
__device__ __forceinline__ float fgelu_(float x){
  const float c = 0.7978845608028654f;
  return 0.5f*x*(1.f + ftanh_(c*(x + 0.044715f*x*x*x)));
}
__device__ __forceinline__ unsigned short f2bf(float x){
  unsigned int u = __float_as_uint(x);
  return (unsigned short)((u + 0x7FFFu + ((u>>16)&1u)) >> 16);
}
__device__ __forceinline__ float bf2f(unsigned short v){
  return __uint_as_float(((unsigned int)v) << 16);
}

// ---------------- weight prep: transposed bf16 B arena, padded to 16-mult segments ----
// Arena layout (bf16 elems):
//  [0..6)      plain msg li:  [160][96]   off = li*15360
//  [6..12)     plain upd li:  [80][160]   off = 92160 + li*12800
//  [12..14)    ar msg blk:    [320][160]  off = 168960 + blk*51200
//  [14..16)    ar upd blk:    [80][320]   off = 271360 + blk*25600
//  [16..18)    gru typ:       [256][128]  off = 322560 + typ*32768
__global__ void k_prepB(const float* __restrict__ Wm_plain, const float* __restrict__ Wu_plain,
                        const float* __restrict__ Wm_ar, const float* __restrict__ Wu_ar,
                        const float* __restrict__ Wi_map, const float* __restrict__ Wh_map,
                        const float* __restrict__ Wi_mem, const float* __restrict__ Wh_mem,
                        unsigned short* __restrict__ BtArena){
  int id = blockIdx.y;
  int Kp, elems, off;
  if (id < 6){ Kp=96;  elems=15360; off=id*15360; }
  else if (id < 12){ Kp=160; elems=12800; off=92160+(id-6)*12800; }
  else if (id < 14){ Kp=160; elems=51200; off=168960+(id-12)*51200; }
  else if (id < 16){ Kp=320; elems=25600; off=271360+(id-14)*25600; }
  else { Kp=128; elems=32768; off=322560+(id-16)*32768; }
  for (int g = blockIdx.x*256 + threadIdx.x; g < elems; g += 8*256){
    int c = g / Kp, k = g - c*Kp;
    float val = 0.f;
    if (id < 6){
      int li = id; int t = (c >= 80); int cc = c - t*80;
      if (cc < 70 && k < 70) val = Wm_plain[((li*2+t)*70 + k)*70 + cc];
    } else if (id < 12){
      int li = id-6;
      int kk = (k < 70) ? k : ((k >= 80 && k < 150) ? 70 + (k-80) : -1);
      if (c < 70 && kk >= 0) val = Wu_plain[(li*140 + kk)*70 + c];
    } else if (id < 14){
      int blk = id-12; int t = (c >= 160); int cc = c - t*160;
      int kk = (k < 70) ? k : ((k >= 80 && k < 150) ? 70 + (k-80) : -1);
      if (cc < 140 && kk >= 0) val = Wm_ar[(((blk*2+t)*140) + kk)*140 + cc];
    } else if (id < 16){
      int blk = id-14;
      int kk = (k < 70) ? k : ((k >= 80 && k < 150) ? 70 + (k-80)
               : ((k >= 160 && k < 300) ? 140 + (k-160) : -1));
      if (c < 70 && kk >= 0) val = Wu_ar[(blk*280 + kk)*70 + c];
    } else {
      int typ = id-16;
      const float* Wi = typ ? Wi_mem : Wi_map;
      const float* Wh = typ ? Wh_mem : Wh_map;
      if (c < 192) val = (k < 64) ? Wi[c*64 + k] : Wh[c*64 + (k-64)];
      else { int cc = c-192; val = (k >= 64) ? Wh[(128+cc)*64 + (k-64)] : 0.f; }
    }
    BtArena[off + g] = f2bf(val);
  }
}

// bias arena (fp32): [0..960) plain msg [160]x6; [960..1440) plain upd [80]x6;
// [1440..2080) ar msg [320]x2; [2080..2240) ar upd [80]x2; [2240..2752) gru [256]x2
__global__ void k_prepBias(const float* __restrict__ bm_plain, const float* __restrict__ bu_plain,
                           const float* __restrict__ bm_ar, const float* __restrict__ bu_ar,
                           const float* __restrict__ bi_map, const float* __restrict__ bh_map,
                           const float* __restrict__ bi_mem, const float* __restrict__ bh_mem,
                           float* __restrict__ biasA){
  for (int g = threadIdx.x; g < 2752; g += 256){
    float val = 0.f;
    if (g < 960){ int li=g/160, c=g%160; int t=(c>=80); int cc=c-t*80;
      if (cc<70) val = bm_plain[(li*2+t)*70 + cc]; }
    else if (g < 1440){ int u=g-960; int li=u/80, c=u%80; if (c<70) val = bu_plain[li*70+c]; }
    else if (g < 2080){ int u=g-1440; int blk=u/320, c=u%320; int t=(c>=160); int cc=c-t*160;
      if (cc<140) val = bm_ar[(blk*2+t)*140 + cc]; }
    else if (g < 2240){ int u=g-2080; int blk=u/80, c=u%80; if (c<70) val = bu_ar[blk*70+c]; }
    else { int u=g-2240; int typ=u/256, c=u%256;
      const float* bi = typ ? bi_mem : bi_map; const float* bh = typ ? bh_mem : bh_map;
      val = (c < 192) ? (bi[c]+bh[c]) : bh[128 + (c-192)]; }
    biasA[g] = val;
  }
}

// ---------------- embed -> bf16 table (1.28 MB, L2-resident for the gather) ----------
__global__ void k_prepEmb(const float* __restrict__ embed, unsigned short* __restrict__ embB,
                          int total){
  int g = blockIdx.x*256 + threadIdx.x;
  if (g < total) embB[g] = f2bf(embed[g]);
}

// ---------------- init h = [one_hot(type,6) | zeros] bf16, stride 80 ----------------
__global__ void k_init_h(const int* __restrict__ type_idx, unsigned short* __restrict__ h, int N){
  int g = blockIdx.x*256 + threadIdx.x;
  if (g >= N*80) return;
  int n = g / 80, c = g - n*80;
  h[g] = (c < 6 && type_idx[n] == c) ? (unsigned short)0x3F80 : (unsigned short)0;
}

__global__ void k_compact(const int* __restrict__ type_idx, int* __restrict__ idxcat,
                          int* __restrict__ cnt, int N){
  int n = blockIdx.x*256 + threadIdx.x;
  if (n >= N) return;
  int t = type_idx[n];
  if (t == 0){ int p = atomicAdd(&cnt[0],1); if (p < CAPT) idxcat[p] = n; }
  else if (t == 5){ int p = atomicAdd(&cnt[1],1); if (p < CAPT) idxcat[CAPT+p] = n; }
}

// ---------------- embed gather: Xemb[r][s][k] bf16, uint4 per thread ----------------
__global__ void k_xemb(const int* __restrict__ idxcat, const int* __restrict__ tokens,
                       const unsigned short* __restrict__ embB, unsigned short* __restrict__ Xemb){
  int g = blockIdx.x*256 + threadIdx.x;          // R2*64 threads
  if (g >= R2*64) return;
  int r = g >> 6, rem = g & 63, s = rem >> 3, ch = rem & 7;
  int nd = idxcat[r]; if (nd < 0) nd = 0;
  int tok = tokens[nd*8 + s];
  *(uint4*)&Xemb[(size_t)g*8] = *(const uint4*)&embB[tok*64 + ch*8];
}

// ---------------- CSR build, per-node edge count padded to multiple of 4 -------------
__global__ void k_count(const int* __restrict__ edst, int* __restrict__ deg, int TE){
  int i = blockIdx.x*256 + threadIdx.x;
  if (i < TE) atomicAdd(&deg[edst[i]], 1);
}
__global__ void k_scan1(const int* __restrict__ deg, int* __restrict__ off,
                        int* __restrict__ bsum, int N){
  __shared__ int sh[256];
  int t = threadIdx.x; int base = blockIdx.x*2048;
  int v[8]; int s = 0;
  for (int i=0;i<8;i++){
    int g = base + t*8 + i;
    int x = (g<N)? (((deg[g]+3)>>2)<<2) : 0;     // pad to x4
    v[i]=x; s+=x;
  }
  sh[t]=s; __syncthreads();
  for (int o=1;o<256;o<<=1){ int x = (t>=o)? sh[t-o]:0; __syncthreads(); sh[t]+=x; __syncthreads(); }
  if (t==255) bsum[blockIdx.x] = sh[255];
  int run = sh[t]-s;
  for (int i=0;i<8;i++){ int g = base + t*8 + i; if (g<N) off[g]=run; run+=v[i]; }
}
__global__ void k_scan2(int* bsum, int nb){
  if (threadIdx.x==0 && blockIdx.x==0){
    int run=0;
    for(int b=0;b<nb;b++){ int x=bsum[b]; bsum[b]=run; run+=x; }
    bsum[nb]=run;                                 // grand total (padded)
  }
}
__global__ void k_scan3(int* __restrict__ off, const int* __restrict__ bsum, int N, int nb){
  int g = blockIdx.x*256+threadIdx.x;
  if (g < N) off[g] += bsum[g>>11];
  if (g == 0) off[N] = bsum[nb];
}
__global__ void k_fill(const int* __restrict__ esrc, const int* __restrict__ edst,
                       const int* __restrict__ off, int* __restrict__ cur,
                       int* __restrict__ edata, int TE, int E){
  int i = blockIdx.x*256 + threadIdx.x;
  if (i >= TE) return;
  int d = edst[i];
  int pos = off[d] + atomicAdd(&cur[d], 1);
  edata[pos] = (esrc[i] << 1) | (i >= E ? 1 : 0);
}
// pad slots [deg, deg4) with a duplicate of the node's first edge (idempotent for max)
__global__ void k_pad(const int* __restrict__ off, const int* __restrict__ cur,
                      int* __restrict__ edata, int N){
  int n = blockIdx.x*256 + threadIdx.x;
  if (n >= N) return;
  int d = cur[n];
  if (d == 0) return;
  int d4 = ((d+3)>>2)<<2;
  int base = off[n];
  int first = edata[base];
  for (int i = d; i < d4; i++) edata[base+i] = first;
}

// ======== wgemm: B-in-registers MFMA GEMM =========================================
// C = act([A0|A1|A2] @ B + bias). mode 1 = GRU (y = row region, B per region).
// act: 0 none, 1 gelu, 2 tanh, 3 = fused GRU cell update (CT==4, mode 1):
//   wave w's col tiles {w,w+4,w+8,w+12} == (r,z,n,hn) pre-activations for u=16w+m;
//   h' = (1-z)*tanh(n + (r-1)*hn) + z*h computed in-register, stored to C[row*64+u].
template<int RTR, int KT, int CT>
__global__ __launch_bounds__(256) void wgemm(
    const unsigned short* __restrict__ A0, int w0, int ldA0,
    const unsigned short* __restrict__ A1, int w1, int ldA1,
    const unsigned short* __restrict__ A2, int w2, int ldA2,
    const unsigned short* __restrict__ Bt, const unsigned short* __restrict__ Bt2, int KpB,
    const float* __restrict__ bias, const float* __restrict__ bias2,
    unsigned short* __restrict__ C, int ldC,
    int rows, int tiles, int act, int mode, const int* __restrict__ cnt)
{
  constexpr int Kpad = KT*32;
  constexpr int NRT  = RTR/16;
  constexpr int CPT  = (RTR*Kpad/8)/256;   // 16B chunks per thread per tile
  __shared__ __align__(16) unsigned short As[2][RTR*Kpad];
  int t = threadIdx.x;
  int lane = t & 63, m = lane & 15, q = lane >> 4, w = t >> 6;
  int rowBase = 0, tileBase = 0, rtEnd;
  const unsigned short* Bsel = Bt; const float* bsel = bias;
  if (mode == 1){
    rowBase = blockIdx.y * CAPT;
    int c = cnt[blockIdx.y]; if (c > CAPT) c = CAPT;
    rtEnd = (c + RTR - 1)/RTR;
    if (blockIdx.y == 1){ Bsel = Bt2; bsel = bias2; }
  } else {
    tileBase = blockIdx.y * (4*CT);
    rtEnd = (rows + RTR - 1)/RTR;
  }
  int tr = blockIdx.x;
  if (tr >= rtEnd) return;

  // ---- B fragments + bias into registers, once per block ----
  short8 breg[CT][KT]; float bv[CT]; bool val[CT]; int colr[CT];
  #pragma unroll
  for (int j=0;j<CT;j++){
    int tt = tileBase + w + 4*j;
    val[j] = (tt < tiles);
    int col = tt*16 + m;
    colr[j] = col;
    bv[j] = 0.f;
    if (val[j]){
      bv[j] = bsel[col];
      #pragma unroll
      for (int kt=0;kt<KT;kt++)
        breg[j][kt] = *(const short8*)&Bsel[(size_t)col*KpB + kt*32 + q*8];
    } else {
      #pragma unroll
      for (int kt=0;kt<KT;kt++) breg[j][kt] = (short8){0,0,0,0,0,0,0,0};
    }
  }

  int w01 = w0 + w1, w012 = w0 + w1 + w2;
  uint4 r[CPT];
  auto loadRegs = [&](int trr){
    #pragma unroll
    for (int i=0;i<CPT;i++){
      int c = i*256 + t;
      int row = c / (KT*4), kc = (c - row*(KT*4))*8;
      int gr = rowBase + trr*RTR + row;
      uint4 v = {0,0,0,0};
      if (gr < rows && kc < w012){
        const unsigned short* sp;
        if (kc < w0)       sp = A0 + (size_t)gr*ldA0 + kc;
        else if (kc < w01) sp = A1 + (size_t)gr*ldA1 + (kc - w0);
        else               sp = A2 + (size_t)gr*ldA2 + (kc - w01);
        v = *(const uint4*)sp;
      }
      r[i] = v;
    }
  };
  auto dsw = [&](int p){
    #pragma unroll
    for (int i=0;i<CPT;i++){
      int c = i*256 + t;
      int row = c / (KT*4), kc = (c - row*(KT*4))*8;
      *(uint4*)&As[p][row*Kpad + kc] = r[i];
    }
  };

  loadRegs(tr);
  dsw(0);
  int p = 0;
  for (;;){
    int nxt = tr + gridDim.x;
    bool hasNext = (nxt < rtEnd);
    if (hasNext) loadRegs(nxt);      // global loads in flight across the barrier
    __syncthreads();                 // buf[p] ready; prior reads of buf[p^1] done
    f32x4 acc[NRT][CT] = {};
    #pragma unroll
    for (int kt=0;kt<KT;kt++){
      short8 af[NRT];
      #pragma unroll
      for (int rt=0;rt<NRT;rt++)
        af[rt] = *(const short8*)&As[p][(rt*16+m)*Kpad + kt*32 + q*8];
      #pragma unroll
      for (int j=0;j<CT;j++)
        #pragma unroll
        for (int rt=0;rt<NRT;rt++)
          acc[rt][j] = __builtin_amdgcn_mfma_f32_16x16x32_bf16(af[rt], breg[j][kt], acc[rt][j], 0,0,0);
    }
    if constexpr (CT == 4){
      if (act == 3){
        // fused GRU cell update; Hprev == A1, u = colr[0], ldC == 64
        int u = colr[0];
        #pragma unroll
        for (int rt=0;rt<NRT;rt++){
          int rbase = rowBase + tr*RTR + rt*16 + q*4;
          #pragma unroll
          for (int i=0;i<4;i++){
            int grow = rbase + i;
            float rr = fsig_(acc[rt][0][i] + bv[0]);
            float zz = fsig_(acc[rt][1][i] + bv[1]);
            float hn = acc[rt][3][i] + bv[3];
            float nn = ftanh_(acc[rt][2][i] + bv[2] + (rr - 1.f)*hn);
            float hp = bf2f(A1[(size_t)grow*64 + u]);
            C[(size_t)grow*64 + u] = f2bf((1.f - zz)*nn + zz*hp);
          }
        }
        if (!hasNext) break;
        dsw(p^1);
        p ^= 1; tr = nxt;
        continue;
      }
    }
    bool tfull = (tr*RTR + RTR <= rows);
#define EPILOG(CHK)                                                         \
    _Pragma("unroll")                                                       \
    for (int rt=0;rt<NRT;rt++){                                             \
      int rbase = rowBase + tr*RTR + rt*16 + q*4;                           \
      _Pragma("unroll")                                                     \
      for (int j=0;j<CT;j++){                                               \
        if (!val[j]) continue;                                              \
        _Pragma("unroll")                                                   \
        for (int i=0;i<4;i++){                                              \
          int grow = rbase + i;                                             \
          if (CHK && grow >= rows) continue;                                \
          float v = acc[rt][j][i] + bv[j];                                  \
          if (act == 1) v = fgelu_(v);                                      \
          else if (act == 2) v = ftanh_(v);                                 \
          C[(size_t)grow*ldC + colr[j]] = f2bf(v);                          \
        }                                                                   \
      }                                                                     \
    }
    if (tfull){ EPILOG(false) } else { EPILOG(true) }
#undef EPILOG
    if (!hasNext) break;
    dsw(p^1);                        // safe: all reads of buf[p^1] were pre-barrier
    p ^= 1; tr = nxt;
  }
}

__global__ void k_scatter_h(const int* __restrict__ idxcat, const unsigned short* __restrict__ Hlast,
                            unsigned short* __restrict__ h){
  int g = blockIdx.x*256 + threadIdx.x;     // R2*64
  int row = g >> 6, u = g & 63;
  int nd = idxcat[row];
  if (nd >= 0) h[(size_t)nd*80 + 6 + u] = Hlast[g];
}

// ---------------- CSR gather + segment max; edge groups of 4 (padded), int4 edata ----
// wide==0: M<=128, lane covers 2 cols (uint). wide==1: M<=256, lane covers 4 (uint2).
__global__ __launch_bounds__(256) void k_aggregate(
    const int* __restrict__ off, const int* __restrict__ edata,
    const unsigned short* __restrict__ P2, int ldP, int off1,
    unsigned short* __restrict__ agg, int M, int N, int wide)
{
  int node = blockIdx.x*4 + (threadIdx.x >> 6);
  int lane = threadIdx.x & 63;
  if (node >= N) return;
  int e0 = off[node], e1 = off[node+1];
  const float NEG = -__builtin_inff();
  float f0 = NEG, f1 = NEG, f2 = NEG, f3 = NEG;
  if (!wide){
    int c = 2*lane;
    bool act = c < M;
    for (int e = e0; e < e1; e += 4){
      int4 w4 = *(const int4*)&edata[e];
      if (act){
        unsigned int u0 = *(const unsigned int*)(P2 + (size_t)(w4.x>>1)*ldP + (w4.x&1)*off1 + c);
        unsigned int u1 = *(const unsigned int*)(P2 + (size_t)(w4.y>>1)*ldP + (w4.y&1)*off1 + c);
        unsigned int u2 = *(const unsigned int*)(P2 + (size_t)(w4.z>>1)*ldP + (w4.z&1)*off1 + c);
        unsigned int u3 = *(const unsigned int*)(P2 + (size_t)(w4.w>>1)*ldP + (w4.w&1)*off1 + c);
        f0 = fmaxf(f0, fmaxf(fmaxf(__uint_as_float(u0<<16), __uint_as_float(u1<<16)),
                             fmaxf(__uint_as_float(u2<<16), __uint_as_float(u3<<16))));
        f1 = fmaxf(f1, fmaxf(fmaxf(__uint_as_float(u0&0xFFFF0000u), __uint_as_float(u1&0xFFFF0000u)),
                             fmaxf(__uint_as_float(u2&0xFFFF0000u), __uint_as_float(u3&0xFFFF0000u))));
      }
    }
    if (act){
      unsigned int o = (__float_as_uint(f0 == NEG ? 0.f : f0) >> 16)
                     |  (__float_as_uint(f1 == NEG ? 0.f : f1) & 0xFFFF0000u);
      *(unsigned int*)(agg + (size_t)node*M + c) = o;
    }
  } else {
    int c = 4*lane;
    bool act = c < M;
    for (int e = e0; e < e1; e += 4){
      int4 w4 = *(const int4*)&edata[e];
      if (act){
        uint2 u0 = *(const uint2*)(P2 + (size_t)(w4.x>>1)*ldP + (w4.x&1)*off1 + c);
        uint2 u1 = *(const uint2*)(P2 + (size_t)(w4.y>>1)*ldP + (w4.y&1)*off1 + c);
        uint2 u2 = *(const uint2*)(P2 + (size_t)(w4.z>>1)*ldP + (w4.z&1)*off1 + c);
        uint2 u3 = *(const uint2*)(P2 + (size_t)(w4.w>>1)*ldP + (w4.w&1)*off1 + c);
        f0 = fmaxf(f0, fmaxf(fmaxf(__uint_as_float(u0.x<<16), __uint_as_float(u1.x<<16)),
                             fmaxf(__uint_as_float(u2.x<<16), __uint_as_float(u3.x<<16))));
        f1 = fmaxf(f1, fmaxf(fmaxf(__uint_as_float(u0.x&0xFFFF0000u), __uint_as_float(u1.x&0xFFFF0000u)),
                             fmaxf(__uint_as_float(u2.x&0xFFFF0000u), __uint_as_float(u3.x&0xFFFF0000u))));
        f2 = fmaxf(f2, fmaxf(fmaxf(__uint_as_float(u0.y<<16), __uint_as_float(u1.y<<16)),
                             fmaxf(__uint_as_float(u2.y<<16), __uint_as_float(u3.y<<16))));
        f3 = fmaxf(f3, fmaxf(fmaxf(__uint_as_float(u0.y&0xFFFF0000u), __uint_as_float(u1.y&0xFFFF0000u)),
                             fmaxf(__uint_as_float(u2.y&0xFFFF0000u), __uint_as_float(u3.y&0xFFFF0000u))));
      }
    }
    if (act){
      uint2 o;
      o.x = (__float_as_uint(f0 == NEG ? 0.f : f0) >> 16)
          |  (__float_as_uint(f1 == NEG ? 0.f : f1) & 0xFFFF0000u);
      o.y = (__float_as_uint(f2 == NEG ? 0.f : f2) >> 16)
          |  (__float_as_uint(f3 == NEG ? 0.f : f3) & 0xFFFF0000u);
      *(uint2*)(agg + (size_t)node*M + c) = o;
    }
  }
}

// ---------------- final head ----------------
__global__ void k_head(const unsigned short* __restrict__ h, const int* __restrict__ entry,
                       const float* __restrict__ W1, const float* __restrict__ b1,
                       const float* __restrict__ W2, const float* __restrict__ b2,
                       float* __restrict__ out){
  __shared__ float x[70], x1[70];
  int t = threadIdx.x;
  if (t < 70) x[t] = bf2f(h[(size_t)(*entry)*80 + t]);
  __syncthreads();
  if (t < 70){
    float s = b1[t];
    for (int i=0;i<70;i++) s += x[i]*W1[i*70 + t];
    x1[t] = fmaxf(s, 0.f);
  }
  __syncthreads();
  if (t < 640){
    float s = b2[t];
    for (int i=0;i<70;i++) s += x1[i]*W2[i*640 + t];
    out[t] = s;
  }
}

extern "C" void kernel_launch(void* const* d_in, const int* in_sizes, int n_in,
                              void* d_out, int out_size, void* d_ws, size_t ws_size,
                              hipStream_t stream) {
  const int*   tokens   = (const int*)d_in[0];
  const int*   type_idx = (const int*)d_in[1];
  const int*   esrc     = (const int*)d_in[2];
  const int*   edst     = (const int*)d_in[3];
  const int*   entry    = (const int*)d_in[4];
  const float* embed    = (const float*)d_in[5];
  const float* Wi_map   = (const float*)d_in[6];
  const float* Wh_map   = (const float*)d_in[7];
  const float* bi_map   = (const float*)d_in[8];
  const float* bh_map   = (const float*)d_in[9];
  const float* Wi_mem   = (const float*)d_in[10];
  const float* Wh_mem   = (const float*)d_in[11];
  const float* bi_mem   = (const float*)d_in[12];
  const float* bh_mem   = (const float*)d_in[13];
  const float* Wm_plain = (const float*)d_in[14];
  const float* bm_plain = (const float*)d_in[15];
  const float* Wu_plain = (const float*)d_in[16];
  const float* bu_plain = (const float*)d_in[17];
  const float* Wm_ar    = (const float*)d_in[18];
  const float* bm_ar    = (const float*)d_in[19];
  const float* Wu_ar    = (const float*)d_in[20];
  const float* bu_ar    = (const float*)d_in[21];
  const float* W1 = (const float*)d_in[22];
  const float* b1 = (const float*)d_in[23];
  const float* W2 = (const float*)d_in[24];
  const float* b2 = (const float*)d_in[25];
  float* out = (float*)d_out;

  const int N  = in_sizes[1];      // 100000
  const int TE = in_sizes[2];      // 500000
  const int E  = TE / 2;
  const int V64 = in_sizes[5];     // V*DE = 640000

  char* p = (char*)d_ws;
  auto alloc = [&](size_t bytes)->char* { char* r = p; p += (bytes + 255) & ~(size_t)255; return r; };
  unsigned short* hA  = (unsigned short*)alloc((size_t)N*80*2);
  unsigned short* hB  = (unsigned short*)alloc((size_t)N*80*2);
  unsigned short* hC  = (unsigned short*)alloc((size_t)N*80*2);
  unsigned short* P2  = (unsigned short*)alloc((size_t)N*320*2);   // also Xemb overlay
  unsigned short* agg = (unsigned short*)alloc((size_t)N*160*2);
  unsigned short* Hb0 = (unsigned short*)alloc((size_t)R2*64*2);
  unsigned short* Hb1 = (unsigned short*)alloc((size_t)R2*64*2);
  int* deg    = (int*)alloc((size_t)N*4);
  int* curp   = (int*)alloc((size_t)N*4);
  int* off    = (int*)alloc((size_t)(N+8)*4);
  int* edata  = (int*)alloc((size_t)(TE + 4*N + 16)*4);            // padded CSR
  int* sbsum  = (int*)alloc(256*4);
  int* cnt    = (int*)alloc(16*4);
  int* idxcat = (int*)alloc((size_t)R2*4);
  unsigned short* BtA  = (unsigned short*)alloc(388096*2);
  float* biasA = (float*)alloc(2752*4);
  unsigned short* embB = (unsigned short*)alloc((size_t)V64*2);
  unsigned short* Xemb = P2;                   // [R2][512] bf16, dead before P2 is used

  hipMemsetAsync(idxcat, 0xFF, (size_t)R2*4, stream);
  hipMemsetAsync(cnt,    0,    16*4, stream);
  hipMemsetAsync(deg,    0,    (size_t)N*4, stream);
  hipMemsetAsync(curp,   0,    (size_t)N*4, stream);
  hipMemsetAsync(Hb0,    0,    (size_t)R2*64*2, stream);

  k_prepB<<<dim3(8,18), 256, 0, stream>>>(Wm_plain, Wu_plain, Wm_ar, Wu_ar,
                                          Wi_map, Wh_map, Wi_mem, Wh_mem, BtA);
  k_prepBias<<<1, 256, 0, stream>>>(bm_plain, bu_plain, bm_ar, bu_ar,
                                    bi_map, bh_map, bi_mem, bh_mem, biasA);
  k_prepEmb<<<(V64+255)/256, 256, 0, stream>>>(embed, embB, V64);
  k_init_h<<<(N*80+255)/256, 256, 0, stream>>>(type_idx, hA, N);
  k_compact<<<(N+255)/256, 256, 0, stream>>>(type_idx, idxcat, cnt, N);

  k_count<<<(TE+255)/256, 256, 0, stream>>>(edst, deg, TE);
  int nb = (N + 2047)/2048;
  k_scan1<<<nb, 256, 0, stream>>>(deg, off, sbsum, N);
  k_scan2<<<1, 64, 0, stream>>>(sbsum, nb);
  k_scan3<<<(N+255)/256, 256, 0, stream>>>(off, sbsum, N, nb);
  k_fill<<<(TE+255)/256, 256, 0, stream>>>(esrc, edst, off, curp, edata, TE, E);
  k_pad<<<(N+255)/256, 256, 0, stream>>>(off, curp, edata, N);

  k_xemb<<<(R2*64+255)/256, 256, 0, stream>>>(idxcat, tokens, embB, Xemb);

  // ---- GRU: 8 steps, pointwise fused into gemm epilogue (act=3) ----
  const unsigned short* BtG0 = BtA + 322560;
  const unsigned short* BtG1 = BtA + 322560 + 32768;
  const float* bG0 = biasA + 2240;
  const float* bG1 = biasA + 2240 + 256;
  unsigned short* Hcur = Hb0; unsigned short* Hnxt = Hb1;
  for (int s = 0; s < 8; s++){
    wgemm<64,4,4><<<dim3(CAPT/64, 2), 256, 0, stream>>>(
        Xemb + s*64, 64, 512,  Hcur, 64, 64,  nullptr, 0, 0,
        BtG0, BtG1, 128, bG0, bG1,
        Hnxt, 64, R2, 16, 3 /*gru fuse*/, 1, cnt);
    unsigned short* tmp = Hcur; Hcur = Hnxt; Hnxt = tmp;
  }
  k_scatter_h<<<(R2*64)/256, 256, 0, stream>>>(idxcat, Hcur, hA);

  // ---- 2 blocks x (3 plain MP + concat-residual AR MP) ----
  unsigned short* cur = hA; unsigned short* f1 = hB; unsigned short* f2 = hC;
  int li = 0;
  for (int blk = 0; blk < 2; blk++){
    unsigned short* saved = cur;
    unsigned short* ins[3]  = {cur, f1, f2};
    unsigned short* outs[3] = {f1, f2, f1};
    for (int j = 0; j < 3; j++){
      unsigned short* X = ins[j]; unsigned short* Yo = outs[j];
      // msg: [N,80] @ [96->160] (both edge types fused in cols)
      wgemm<64,3,3><<<dim3(1024,1), 256, 0, stream>>>(
          X, 80, 80,  nullptr, 0, 0,  nullptr, 0, 0,
          BtA + li*15360, nullptr, 96, biasA + li*160, nullptr,
          P2, 160, N, 10, 0, 0, nullptr);
      k_aggregate<<<(N+3)/4, 256, 0, stream>>>(off, edata, P2, 160, 80, agg, 80, N, 0);
      // upd: [N,80|80] @ [160->80]
      wgemm<64,5,2><<<dim3(1024,1), 256, 0, stream>>>(
          X, 80, 80,  agg, 80, 80,  nullptr, 0, 0,
          BtA + 92160 + li*12800, nullptr, 160, biasA + 960 + li*80, nullptr,
          Yo, 80, N, 5, 0, 0, nullptr);
      li++;
    }
    // AR msg: [N,80|80] @ [160->320], gelu; y splits 20 col tiles into 12+8
    wgemm<64,5,3><<<dim3(512,2), 256, 0, stream>>>(
        saved, 80, 80,  f1, 80, 80,  nullptr, 0, 0,
        BtA + 168960 + blk*51200, nullptr, 160, biasA + 1440 + blk*320, nullptr,
        P2, 320, N, 20, 1 /*gelu*/, 0, nullptr);
    k_aggregate<<<(N+3)/4, 256, 0, stream>>>(off, edata, P2, 320, 160, agg, 160, N, 1);
    // AR upd: [N,80|80|160] @ [320->80], tanh; 32-row tiles (K=320 LDS)
    wgemm<32,10,2><<<dim3(1024,1), 256, 0, stream>>>(
        saved, 80, 80,  f1, 80, 80,  agg, 160, 160,
        BtA + 271360 + blk*25600, nullptr, 320, biasA + 2080 + blk*80, nullptr,
        f2, 80, N, 5, 2 /*tanh*/, 0, nullptr);
    unsigned short* t3 = cur; cur = f2; f2 = t3;
  }

  k_head<<<1, 640, 0, stream>>>(cur, entry, W1, b1, W2, b2, out);
}